// Round 1
// baseline (979.913 us; speedup 1.0000x reference)
//
#include <hip/hip_runtime.h>

#define VV 9
#define CC 24
#define HFF 120
#define WFF 160
#define HW (HFF*WFF)
#define NPAIR 45
#define SIMDIM 72

// index into packed upper triangle (a<=b), 9x9
__device__ __host__ __forceinline__ constexpr int triidx(int a, int b) {
  return a * VV - a * (a - 1) / 2 + (b - a);
}

__device__ __forceinline__ float4 blend4(const float* bp, int dx, int dy,
                                         float w00, float w01, float w10, float w11) {
  float4 a = *(const float4*)(bp);
  float4 b = *(const float4*)(bp + dx);
  float4 c = *(const float4*)(bp + dy);
  float4 d = *(const float4*)(bp + dx + dy);
  float4 r;
  r.x = w00 * a.x + w01 * b.x + w10 * c.x + w11 * d.x;
  r.y = w00 * a.y + w01 * b.y + w10 * c.y + w11 * d.y;
  r.z = w00 * a.z + w01 * b.z + w10 * c.z + w11 * d.z;
  r.w = w00 * a.w + w01 * b.w + w10 * c.w + w11 * d.w;
  return r;
}

// (V,C,H,W) -> (V,H,W,C)
__global__ __launch_bounds__(256)
void vf_transpose(const float* __restrict__ feats, float* __restrict__ tf, int total) {
  int i = blockIdx.x * 256 + threadIdx.x;
  if (i >= total) return;
  int v = i / HW;
  int hw = i - v * HW;
  const float* s = feats + (size_t)v * CC * HW + hw;
  float4* d = (float4*)(tf + (size_t)i * CC);
#pragma unroll
  for (int c4 = 0; c4 < CC / 4; ++c4) {
    float4 o;
    o.x = s[(size_t)(c4 * 4 + 0) * HW];
    o.y = s[(size_t)(c4 * 4 + 1) * HW];
    o.z = s[(size_t)(c4 * 4 + 2) * HW];
    o.w = s[(size_t)(c4 * 4 + 3) * HW];
    d[c4] = o;
  }
}

template <bool TR>
__global__ __launch_bounds__(256, 2)
void vf_main(const int* __restrict__ coords,
             const float* __restrict__ feats,
             const float* __restrict__ tfeats,
             const float* __restrict__ proj_feat,
             const float* __restrict__ proj_img,
             const float* __restrict__ origin,
             const float* __restrict__ W_vs,
             const float* __restrict__ b_vs,
             const float* __restrict__ voxel_size,
             const int* __restrict__ scale,
             const int* __restrict__ im_h_p,
             const int* __restrict__ im_w_p,
             float* __restrict__ out,
             double* __restrict__ partials,
             int n) {
  __shared__ float sPF[VV * 12], sPI[VV * 12], sW[SIMDIM * VV], sB[VV];
  __shared__ double sRed[3][4];

  for (int t = threadIdx.x; t < VV * 12; t += 256) {
    int v = t / 12, r = t - v * 12;
    sPF[t] = proj_feat[v * 16 + r];
    sPI[t] = proj_img[v * 16 + r];
  }
  for (int t = threadIdx.x; t < SIMDIM * VV; t += 256) sW[t] = W_vs[t];
  if (threadIdx.x < VV) sB[threadIdx.x] = b_vs[threadIdx.x];
  __syncthreads();

  int i = blockIdx.x * 256 + threadIdx.x;
  bool active = i < n;
  float zmean = 0.f;

  if (active) {
    float vs = voxel_size[0];
    float half = ldexpf(0.5f * vs, scale[0]);
    float wxp = (float)coords[i * 4 + 1] * vs + origin[0];
    float wyp = (float)coords[i * 4 + 2] * vs + origin[1];
    float wzp = (float)coords[i * 4 + 3] * vs + origin[2];
    float imw1 = (float)(im_w_p[0] - 1), imh1 = (float)(im_h_p[0] - 1);

    int base[VV], dxo[VV], dyo[VV];
    float fx[VV], wa[VV], wb[VV], mk[VV];
    float zsum = 0.f, msum = 0.f;

#pragma unroll
    for (int v = 0; v < VV; ++v) {
      const float* M = &sPF[v * 12];
      float px = M[0] * wxp + M[1] * wyp + M[2] * wzp + M[3];
      float py = M[4] * wxp + M[5] * wyp + M[6] * wzp + M[7];
      float pz = M[8] * wxp + M[9] * wyp + M[10] * wzp + M[11];
      const float* P = &sPI[v * 12];
      float qx = P[0] * wxp + P[1] * wyp + P[2] * wzp + P[3];
      float qy = P[4] * wxp + P[5] * wyp + P[6] * wzp + P[7];
      float qz = P[8] * wxp + P[9] * wyp + P[10] * wzp + P[11];
      float h0x = P[0] * half, h1x = P[1] * half, h2x = P[2] * half;
      float h0y = P[4] * half, h1y = P[5] * half, h2y = P[6] * half;
      float h0z = P[8] * half, h1z = P[9] * half, h2z = P[10] * half;
      bool m = false;
#pragma unroll
      for (int k = 0; k < 8; ++k) {
        float s0 = (k & 1) ? -1.f : 1.f;
        float s1 = (k & 2) ? -1.f : 1.f;
        float s2 = (k & 4) ? -1.f : 1.f;
        float X = qx + s0 * h0x + s1 * h1x + s2 * h2x;
        float Y = qy + s0 * h0y + s1 * h1y + s2 * h2y;
        float Z = qz + s0 * h0z + s1 * h1z + s2 * h2z;
        float gxc = 2.f * (X / Z) / imw1 - 1.f;
        float gyc = 2.f * (Y / Z) / imh1 - 1.f;
        m = m || (fabsf(gxc) <= 1.1f && fabsf(gyc) <= 1.1f && Z > 0.f);
      }
      float mkv = m ? 1.f : 0.f;
      mk[v] = mkv;
      zsum += pz * mkv;
      msum += mkv;

      float x = fminf(fmaxf(px / pz, 0.f), (float)(WFF - 1));
      float y = fminf(fmaxf(py / pz, 0.f), (float)(HFF - 1));
      float x0f = floorf(x), y0f = floorf(y);
      float fxv = x - x0f, fyv = y - y0f;
      int x0 = (int)x0f, y0 = (int)y0f;
      x0 = min(max(x0, 0), WFF - 1);
      y0 = min(max(y0, 0), HFF - 1);
      int x1 = min(x0 + 1, WFF - 1), y1 = min(y0 + 1, HFF - 1);
      if (TR) {
        base[v] = ((v * HFF + y0) * WFF + x0) * CC;
        dxo[v] = (x1 - x0) * CC;
        dyo[v] = (y1 - y0) * WFF * CC;
      } else {
        base[v] = v * CC * HW + y0 * WFF + x0;
        dxo[v] = (x1 - x0);
        dyo[v] = (y1 - y0) * WFF;
      }
      fx[v] = fxv;
      wa[v] = (1.f - fyv) * mkv;  // mask folded into sample weights
      wb[v] = fyv * mkv;
    }
    zmean = zsum / (msum + 1e-10f);

    // ---- pass A: gram accumulation ----
    float gram[NPAIR];
#pragma unroll
    for (int p = 0; p < NPAIR; ++p) gram[p] = 0.f;

    if (TR) {
#pragma unroll
      for (int cc = 0; cc < CC; cc += 4) {
        float4 f[VV];
#pragma unroll
        for (int v = 0; v < VV; ++v) {
          float w00 = (1.f - fx[v]) * wa[v], w01 = fx[v] * wa[v];
          float w10 = (1.f - fx[v]) * wb[v], w11 = fx[v] * wb[v];
          f[v] = blend4(tfeats + base[v] + cc, dxo[v], dyo[v], w00, w01, w10, w11);
        }
        int p = 0;
#pragma unroll
        for (int v = 0; v < VV; ++v)
#pragma unroll
          for (int w = v; w < VV; ++w, ++p)
            gram[p] += f[v].x * f[w].x + f[v].y * f[w].y + f[v].z * f[w].z + f[v].w * f[w].w;
      }
    } else {
#pragma unroll 2
      for (int c = 0; c < CC; ++c) {
        float fv[VV];
#pragma unroll
        for (int v = 0; v < VV; ++v) {
          const float* bp = feats + base[v] + c * HW;
          float w00 = (1.f - fx[v]) * wa[v], w01 = fx[v] * wa[v];
          float w10 = (1.f - fx[v]) * wb[v], w11 = fx[v] * wb[v];
          fv[v] = w00 * bp[0] + w01 * bp[dxo[v]] + w10 * bp[dyo[v]] + w11 * bp[dxo[v] + dyo[v]];
        }
        int p = 0;
#pragma unroll
        for (int v = 0; v < VV; ++v)
#pragma unroll
          for (int w = v; w < VV; ++w, ++p) gram[p] += fv[v] * fv[w];
      }
    }

    // ---- norms, similarity -> logits ----
    float inv[VV];
#pragma unroll
    for (int v = 0; v < VV; ++v) inv[v] = 1.f / (sqrtf(gram[triidx(v, v)]) + 1e-10f);

    float logit[VV];
#pragma unroll
    for (int j = 0; j < VV; ++j) logit[j] = sB[j];
    int k = 0;
#pragma unroll
    for (int v = 0; v < VV; ++v) {
#pragma unroll
      for (int w = 0; w < VV; ++w) {
        if (w == v) continue;
        int a = v < w ? v : w, b2 = v < w ? w : v;
        float s = gram[triidx(a, b2)] * inv[v] * inv[w];
#pragma unroll
        for (int j = 0; j < VV; ++j) logit[j] += s * sW[k * VV + j];
        ++k;
      }
    }

    // softmax * mask
    float mx = logit[0];
#pragma unroll
    for (int j = 1; j < VV; ++j) mx = fmaxf(mx, logit[j]);
    float wt[VV], se = 0.f;
#pragma unroll
    for (int j = 0; j < VV; ++j) {
      wt[j] = __expf(logit[j] - mx);
      se += wt[j];
    }
    float rse = 1.f / se;
#pragma unroll
    for (int j = 0; j < VV; ++j) wt[j] = wt[j] * rse * mk[j];

    // ---- pass B: fused features (re-sample, cache-hot) ----
    float* fvrow = out + (size_t)i * (CC + 1);
    if (TR) {
#pragma unroll
      for (int cc = 0; cc < CC; cc += 4) {
        float a0 = 0.f, a1 = 0.f, a2 = 0.f, a3 = 0.f;
#pragma unroll
        for (int v = 0; v < VV; ++v) {
          float w00 = (1.f - fx[v]) * wa[v], w01 = fx[v] * wa[v];
          float w10 = (1.f - fx[v]) * wb[v], w11 = fx[v] * wb[v];
          float4 r = blend4(tfeats + base[v] + cc, dxo[v], dyo[v], w00, w01, w10, w11);
          a0 += wt[v] * r.x;
          a1 += wt[v] * r.y;
          a2 += wt[v] * r.z;
          a3 += wt[v] * r.w;
        }
        fvrow[cc + 0] = a0;
        fvrow[cc + 1] = a1;
        fvrow[cc + 2] = a2;
        fvrow[cc + 3] = a3;
      }
    } else {
#pragma unroll 2
      for (int c = 0; c < CC; ++c) {
        float acc = 0.f;
#pragma unroll
        for (int v = 0; v < VV; ++v) {
          const float* bp = feats + base[v] + c * HW;
          float w00 = (1.f - fx[v]) * wa[v], w01 = fx[v] * wa[v];
          float w10 = (1.f - fx[v]) * wb[v], w11 = fx[v] * wb[v];
          float s = w00 * bp[0] + w01 * bp[dxo[v]] + w10 * bp[dyo[v]] + w11 * bp[dxo[v] + dyo[v]];
          acc += wt[v] * s;
        }
        fvrow[c] = acc;
      }
    }
    fvrow[CC] = zmean;  // stash zmean; kernel 3 rewrites with z_norm

    float* vwrow = out + (size_t)n * (CC + 1) + (size_t)i * VV;
#pragma unroll
    for (int j = 0; j < VV; ++j) vwrow[j] = wt[j];
    out[(size_t)n * (CC + 1) + (size_t)n * VV + i] = msum;
  }

  // ---- block reduction of z statistics (deterministic, no atomics) ----
  float zm = active ? zmean : 0.f;
  bool pos = zm > 0.f;
  double s = pos ? (double)zm : 0.0;
  double ss = pos ? (double)zm * (double)zm : 0.0;
  double cn = pos ? 1.0 : 0.0;
#pragma unroll
  for (int off = 32; off > 0; off >>= 1) {
    s += __shfl_down(s, off);
    ss += __shfl_down(ss, off);
    cn += __shfl_down(cn, off);
  }
  int wid = threadIdx.x >> 6, lane = threadIdx.x & 63;
  if (lane == 0) {
    sRed[0][wid] = s;
    sRed[1][wid] = ss;
    sRed[2][wid] = cn;
  }
  __syncthreads();
  if (threadIdx.x == 0) {
    double S = 0, SS = 0, CN = 0;
    for (int w2 = 0; w2 < 4; ++w2) {
      S += sRed[0][w2];
      SS += sRed[1][w2];
      CN += sRed[2][w2];
    }
    partials[blockIdx.x * 3 + 0] = S;
    partials[blockIdx.x * 3 + 1] = SS;
    partials[blockIdx.x * 3 + 2] = CN;
  }
}

__global__ __launch_bounds__(256)
void vf_reduce(const double* __restrict__ partials, int nb, float* __restrict__ musd) {
  __shared__ double sh[3][4];
  double s = 0, ss = 0, cn = 0;
  for (int b = threadIdx.x; b < nb; b += 256) {
    s += partials[b * 3 + 0];
    ss += partials[b * 3 + 1];
    cn += partials[b * 3 + 2];
  }
#pragma unroll
  for (int off = 32; off > 0; off >>= 1) {
    s += __shfl_down(s, off);
    ss += __shfl_down(ss, off);
    cn += __shfl_down(cn, off);
  }
  int wid = threadIdx.x >> 6, lane = threadIdx.x & 63;
  if (lane == 0) {
    sh[0][wid] = s;
    sh[1][wid] = ss;
    sh[2][wid] = cn;
  }
  __syncthreads();
  if (threadIdx.x == 0) {
    double S = 0, SS = 0, CN = 0;
    for (int w2 = 0; w2 < 4; ++w2) {
      S += sh[0][w2];
      SS += sh[1][w2];
      CN += sh[2][w2];
    }
    double cnt = CN < 1.0 ? 1.0 : CN;
    double mu = S / cnt;
    double ssd = SS - 2.0 * mu * S + mu * mu * CN;
    if (ssd < 0.0) ssd = 0.0;
    double sd = sqrt(ssd) + 1e-5;
    musd[0] = (float)mu;
    musd[1] = (float)sd;
  }
}

__global__ __launch_bounds__(256)
void vf_znorm(float* __restrict__ out, const float* __restrict__ musd, int n) {
  int i = blockIdx.x * 256 + threadIdx.x;
  if (i >= n) return;
  float z = out[(size_t)i * (CC + 1) + CC];
  float mu = musd[0], sd = musd[1];
  out[(size_t)i * (CC + 1) + CC] = (z > 0.f) ? (z - mu) / sd : 0.f;
}

extern "C" void kernel_launch(void* const* d_in, const int* in_sizes, int n_in,
                              void* d_out, int out_size, void* d_ws, size_t ws_size,
                              hipStream_t stream) {
  const int* coords = (const int*)d_in[0];
  const float* feats = (const float*)d_in[1];
  const float* proj_feat = (const float*)d_in[2];
  const float* proj_img = (const float*)d_in[3];
  const float* origin = (const float*)d_in[4];
  const float* W_vs = (const float*)d_in[5];
  const float* b_vs = (const float*)d_in[6];
  const float* voxel_size = (const float*)d_in[7];
  const int* scale = (const int*)d_in[8];
  const int* im_h = (const int*)d_in[9];
  const int* im_w = (const int*)d_in[10];

  int n = in_sizes[0] / 4;
  int nb = (n + 255) / 256;

  float* musd = (float*)d_ws;
  double* partials = (double*)((char*)d_ws + 256);
  size_t tf_off = (256 + (size_t)nb * 3 * 8 + 255) & ~(size_t)255;
  size_t tf_bytes = (size_t)VV * HW * CC * 4;
  bool use_tr = (ws_size >= tf_off + tf_bytes);
  float* tfeats = (float*)((char*)d_ws + tf_off);

  if (use_tr) {
    int total = VV * HW;
    vf_transpose<<<dim3((total + 255) / 256), dim3(256), 0, stream>>>(feats, tfeats, total);
    vf_main<true><<<dim3(nb), dim3(256), 0, stream>>>(
        coords, feats, tfeats, proj_feat, proj_img, origin, W_vs, b_vs, voxel_size,
        scale, im_h, im_w, (float*)d_out, partials, n);
  } else {
    vf_main<false><<<dim3(nb), dim3(256), 0, stream>>>(
        coords, feats, feats, proj_feat, proj_img, origin, W_vs, b_vs, voxel_size,
        scale, im_h, im_w, (float*)d_out, partials, n);
  }
  vf_reduce<<<dim3(1), dim3(256), 0, stream>>>(partials, nb, musd);
  vf_znorm<<<dim3(nb), dim3(256), 0, stream>>>((float*)d_out, musd, n);
}

// Round 2
// 194.271 us; speedup vs baseline: 5.0440x; 5.0440x over previous
//
#include <hip/hip_runtime.h>

#define VV 9
#define CC 24
#define HFF 120
#define WFF 160
#define HW (HFF*WFF)
#define NPAIR 45
#define SIMDIM 72
#define CPL 6   // channels per lane (quad scheme)

// index into packed upper triangle (a<=b), 9x9
__device__ __host__ __forceinline__ constexpr int triidx(int a, int b) {
  return a * VV - a * (a - 1) / 2 + (b - a);
}

// (V,C,H,W) -> (V,H,W,C)
__global__ __launch_bounds__(256)
void vf_transpose(const float* __restrict__ feats, float* __restrict__ tf, int total) {
  int i = blockIdx.x * 256 + threadIdx.x;
  if (i >= total) return;
  int v = i / HW;
  int hw = i - v * HW;
  const float* s = feats + (size_t)v * CC * HW + hw;
  float4* d = (float4*)(tf + (size_t)i * CC);
#pragma unroll
  for (int c4 = 0; c4 < CC / 4; ++c4) {
    float4 o;
    o.x = s[(size_t)(c4 * 4 + 0) * HW];
    o.y = s[(size_t)(c4 * 4 + 1) * HW];
    o.z = s[(size_t)(c4 * 4 + 2) * HW];
    o.w = s[(size_t)(c4 * 4 + 3) * HW];
    d[c4] = o;
  }
}

// ---------------- quad kernel: 4 lanes per voxel, 64 voxels per block ----------------
__global__ __launch_bounds__(256)
void vf_main4(const int* __restrict__ coords,
              const float* __restrict__ tfeats,
              const float* __restrict__ proj_feat,
              const float* __restrict__ proj_img,
              const float* __restrict__ origin,
              const float* __restrict__ W_vs,
              const float* __restrict__ b_vs,
              const float* __restrict__ voxel_size,
              const int* __restrict__ scale,
              const int* __restrict__ im_h_p,
              const int* __restrict__ im_w_p,
              float* __restrict__ out,
              double* __restrict__ partials,
              int n) {
  __shared__ float sPF[VV * 12], sPI[VV * 12], sW[SIMDIM * VV], sB[VV];
  __shared__ float4 sFV4[64 * 25 / 4 + 1];   // 64 voxels x 25 floats
  __shared__ float4 sVW4[64 * 9 / 4];        // 64 voxels x 9 floats
  __shared__ float sCNT[64];
  __shared__ double sRed[3][4];
  float* sFV = (float*)sFV4;
  float* sVW = (float*)sVW4;

  int tid = threadIdx.x;
  for (int t = tid; t < VV * 12; t += 256) {
    int v = t / 12, r = t - v * 12;
    sPF[t] = proj_feat[v * 16 + r];
    sPI[t] = proj_img[v * 16 + r];
  }
  for (int t = tid; t < SIMDIM * VV; t += 256) sW[t] = W_vs[t];
  if (tid < VV) sB[tid] = b_vs[tid];
  __syncthreads();

  int lr = tid & 3;           // lane-in-quad: channels [6*lr, 6*lr+6)
  int vloc = tid >> 2;        // local voxel 0..63
  int vox = blockIdx.x * 64 + vloc;
  bool active = vox < n;
  float zmean = 0.f;

  float f[VV][CPL];           // masked sampled features for this lane's channels
  float mk[VV];
  float msum = 0.f;

  if (active) {
    float vs = voxel_size[0];
    float half = ldexpf(0.5f * vs, scale[0]);
    float wxp = (float)coords[vox * 4 + 1] * vs + origin[0];
    float wyp = (float)coords[vox * 4 + 2] * vs + origin[1];
    float wzp = (float)coords[vox * 4 + 3] * vs + origin[2];
    float imw1 = (float)(im_w_p[0] - 1), imh1 = (float)(im_h_p[0] - 1);
    float zsum = 0.f;

#pragma unroll
    for (int v = 0; v < VV; ++v) {
      const float* M = &sPF[v * 12];
      float px = M[0] * wxp + M[1] * wyp + M[2] * wzp + M[3];
      float py = M[4] * wxp + M[5] * wyp + M[6] * wzp + M[7];
      float pz = M[8] * wxp + M[9] * wyp + M[10] * wzp + M[11];
      const float* P = &sPI[v * 12];
      float qx = P[0] * wxp + P[1] * wyp + P[2] * wzp + P[3];
      float qy = P[4] * wxp + P[5] * wyp + P[6] * wzp + P[7];
      float qz = P[8] * wxp + P[9] * wyp + P[10] * wzp + P[11];
      float h0x = P[0] * half, h1x = P[1] * half, h2x = P[2] * half;
      float h0y = P[4] * half, h1y = P[5] * half, h2y = P[6] * half;
      float h0z = P[8] * half, h1z = P[9] * half, h2z = P[10] * half;
      bool m = false;
#pragma unroll
      for (int k = 0; k < 8; ++k) {
        float s0 = (k & 1) ? -1.f : 1.f;
        float s1 = (k & 2) ? -1.f : 1.f;
        float s2 = (k & 4) ? -1.f : 1.f;
        float X = qx + s0 * h0x + s1 * h1x + s2 * h2x;
        float Y = qy + s0 * h0y + s1 * h1y + s2 * h2y;
        float Z = qz + s0 * h0z + s1 * h1z + s2 * h2z;
        float gxc = 2.f * (X / Z) / imw1 - 1.f;
        float gyc = 2.f * (Y / Z) / imh1 - 1.f;
        m = m || (fabsf(gxc) <= 1.1f && fabsf(gyc) <= 1.1f && Z > 0.f);
      }
      float mkv = m ? 1.f : 0.f;
      mk[v] = mkv;
      zsum += pz * mkv;
      msum += mkv;

      float x = fminf(fmaxf(px / pz, 0.f), (float)(WFF - 1));
      float y = fminf(fmaxf(py / pz, 0.f), (float)(HFF - 1));
      float x0f = floorf(x), y0f = floorf(y);
      float fxv = x - x0f, fyv = y - y0f;
      int x0 = (int)x0f, y0 = (int)y0f;
      x0 = min(max(x0, 0), WFF - 1);
      y0 = min(max(y0, 0), HFF - 1);
      int x1 = min(x0 + 1, WFF - 1), y1 = min(y0 + 1, HFF - 1);
      int base = ((v * HFF + y0) * WFF + x0) * CC + CPL * lr;
      int dxo = (x1 - x0) * CC;
      int dyo = (y1 - y0) * WFF * CC;
      float w00 = (1.f - fxv) * (1.f - fyv) * mkv;
      float w01 = fxv * (1.f - fyv) * mkv;
      float w10 = (1.f - fxv) * fyv * mkv;
      float w11 = fxv * fyv * mkv;

      const float* bp = tfeats + base;
#pragma unroll
      for (int j = 0; j < CPL / 2; ++j) {
        float2 a = *(const float2*)(bp + 2 * j);
        float2 b = *(const float2*)(bp + dxo + 2 * j);
        float2 c = *(const float2*)(bp + dyo + 2 * j);
        float2 d = *(const float2*)(bp + dxo + dyo + 2 * j);
        f[v][2 * j + 0] = w00 * a.x + w01 * b.x + w10 * c.x + w11 * d.x;
        f[v][2 * j + 1] = w00 * a.y + w01 * b.y + w10 * c.y + w11 * d.y;
      }
    }
    zmean = zsum / (msum + 1e-10f);
  } else {
#pragma unroll
    for (int v = 0; v < VV; ++v) {
      mk[v] = 0.f;
#pragma unroll
      for (int c = 0; c < CPL; ++c) f[v][c] = 0.f;
    }
  }

  // ---- partial gram over this lane's 6 channels ----
  float gram[NPAIR];
  {
    int p = 0;
#pragma unroll
    for (int v = 0; v < VV; ++v)
#pragma unroll
      for (int w = v; w < VV; ++w, ++p) {
        float s = 0.f;
#pragma unroll
        for (int c = 0; c < CPL; ++c) s += f[v][c] * f[w][c];
        gram[p] = s;
      }
  }
  // quad butterfly reduce (lanes differing in bits 0,1 belong to same voxel)
#pragma unroll
  for (int p = 0; p < NPAIR; ++p) {
    gram[p] += __shfl_xor(gram[p], 1);
    gram[p] += __shfl_xor(gram[p], 2);
  }

  if (active) {
    float inv[VV];
#pragma unroll
    for (int v = 0; v < VV; ++v) inv[v] = 1.f / (sqrtf(gram[triidx(v, v)]) + 1e-10f);

    float logit[VV];
#pragma unroll
    for (int j = 0; j < VV; ++j) logit[j] = sB[j];
    int k = 0;
#pragma unroll
    for (int v = 0; v < VV; ++v) {
#pragma unroll
      for (int w = 0; w < VV; ++w) {
        if (w == v) continue;
        int a = v < w ? v : w, b2 = v < w ? w : v;
        float s = gram[triidx(a, b2)] * inv[v] * inv[w];
#pragma unroll
        for (int j = 0; j < VV; ++j) logit[j] += s * sW[k * VV + j];
        ++k;
      }
    }

    float mx = logit[0];
#pragma unroll
    for (int j = 1; j < VV; ++j) mx = fmaxf(mx, logit[j]);
    float wt[VV], se = 0.f;
#pragma unroll
    for (int j = 0; j < VV; ++j) {
      wt[j] = __expf(logit[j] - mx);
      se += wt[j];
    }
    float rse = 1.f / se;
#pragma unroll
    for (int j = 0; j < VV; ++j) wt[j] = wt[j] * rse * mk[j];

    // fused features for this lane's 6 channels (from registers; no reload)
#pragma unroll
    for (int c = 0; c < CPL; ++c) {
      float acc = 0.f;
#pragma unroll
      for (int v = 0; v < VV; ++v) acc += wt[v] * f[v][c];
      sFV[vloc * 25 + CPL * lr + c] = acc;
    }
    if (lr == 0) {
      sFV[vloc * 25 + CC] = zmean;  // stash zmean; rewritten by vf_znorm
#pragma unroll
      for (int j = 0; j < VV; ++j) sVW[vloc * 9 + j] = wt[j];
      sCNT[vloc] = msum;
    }
  }

  // ---- block reduction of z statistics (one contribution per voxel) ----
  float zm = (active && lr == 0) ? zmean : 0.f;
  bool pos = zm > 0.f;
  double s = pos ? (double)zm : 0.0;
  double ss = pos ? (double)zm * (double)zm : 0.0;
  double cn = pos ? 1.0 : 0.0;
#pragma unroll
  for (int off = 32; off > 0; off >>= 1) {
    s += __shfl_down(s, off);
    ss += __shfl_down(ss, off);
    cn += __shfl_down(cn, off);
  }
  int wid = tid >> 6, lane = tid & 63;
  if (lane == 0) {
    sRed[0][wid] = s;
    sRed[1][wid] = ss;
    sRed[2][wid] = cn;
  }
  __syncthreads();
  if (tid == 0) {
    double S = 0, SS = 0, CN = 0;
    for (int w2 = 0; w2 < 4; ++w2) {
      S += sRed[0][w2];
      SS += sRed[1][w2];
      CN += sRed[2][w2];
    }
    partials[blockIdx.x * 3 + 0] = S;
    partials[blockIdx.x * 3 + 1] = SS;
    partials[blockIdx.x * 3 + 2] = CN;
  }

  // ---- coalesced output writes via LDS staging ----
  int vb = blockIdx.x * 64;
  int cv = min(64, n - vb);
  if (cv == 64) {
    float4* dfv = (float4*)(out + (size_t)vb * 25);
    for (int t = tid; t < 400; t += 256) dfv[t] = sFV4[t];
    float4* dvw = (float4*)(out + (size_t)n * 25 + (size_t)vb * 9);
    for (int t = tid; t < 144; t += 256) dvw[t] = sVW4[t];
    if (tid < 64) out[(size_t)n * 34 + vb + tid] = sCNT[tid];
  } else if (cv > 0) {
    for (int t = tid; t < cv * 25; t += 256) out[(size_t)vb * 25 + t] = sFV[t];
    for (int t = tid; t < cv * 9; t += 256) out[(size_t)n * 25 + (size_t)vb * 9 + t] = sVW[t];
    if (tid < cv) out[(size_t)n * 34 + vb + tid] = sCNT[tid];
  }
}

// ---------------- fallback (1 thread/voxel, original layout) ----------------
__global__ __launch_bounds__(256, 2)
void vf_main_fb(const int* __restrict__ coords,
                const float* __restrict__ feats,
                const float* __restrict__ proj_feat,
                const float* __restrict__ proj_img,
                const float* __restrict__ origin,
                const float* __restrict__ W_vs,
                const float* __restrict__ b_vs,
                const float* __restrict__ voxel_size,
                const int* __restrict__ scale,
                const int* __restrict__ im_h_p,
                const int* __restrict__ im_w_p,
                float* __restrict__ out,
                double* __restrict__ partials,
                int n) {
  __shared__ float sPF[VV * 12], sPI[VV * 12], sW[SIMDIM * VV], sB[VV];
  __shared__ double sRed[3][4];

  for (int t = threadIdx.x; t < VV * 12; t += 256) {
    int v = t / 12, r = t - v * 12;
    sPF[t] = proj_feat[v * 16 + r];
    sPI[t] = proj_img[v * 16 + r];
  }
  for (int t = threadIdx.x; t < SIMDIM * VV; t += 256) sW[t] = W_vs[t];
  if (threadIdx.x < VV) sB[threadIdx.x] = b_vs[threadIdx.x];
  __syncthreads();

  int i = blockIdx.x * 256 + threadIdx.x;
  bool active = i < n;
  float zmean = 0.f;

  if (active) {
    float vs = voxel_size[0];
    float half = ldexpf(0.5f * vs, scale[0]);
    float wxp = (float)coords[i * 4 + 1] * vs + origin[0];
    float wyp = (float)coords[i * 4 + 2] * vs + origin[1];
    float wzp = (float)coords[i * 4 + 3] * vs + origin[2];
    float imw1 = (float)(im_w_p[0] - 1), imh1 = (float)(im_h_p[0] - 1);

    int base[VV], dxo[VV], dyo[VV];
    float fx[VV], wa[VV], wb[VV], mk[VV];
    float zsum = 0.f, msum = 0.f;

#pragma unroll
    for (int v = 0; v < VV; ++v) {
      const float* M = &sPF[v * 12];
      float px = M[0] * wxp + M[1] * wyp + M[2] * wzp + M[3];
      float py = M[4] * wxp + M[5] * wyp + M[6] * wzp + M[7];
      float pz = M[8] * wxp + M[9] * wyp + M[10] * wzp + M[11];
      const float* P = &sPI[v * 12];
      float qx = P[0] * wxp + P[1] * wyp + P[2] * wzp + P[3];
      float qy = P[4] * wxp + P[5] * wyp + P[6] * wzp + P[7];
      float qz = P[8] * wxp + P[9] * wyp + P[10] * wzp + P[11];
      float h0x = P[0] * half, h1x = P[1] * half, h2x = P[2] * half;
      float h0y = P[4] * half, h1y = P[5] * half, h2y = P[6] * half;
      float h0z = P[8] * half, h1z = P[9] * half, h2z = P[10] * half;
      bool m = false;
#pragma unroll
      for (int k = 0; k < 8; ++k) {
        float s0 = (k & 1) ? -1.f : 1.f;
        float s1 = (k & 2) ? -1.f : 1.f;
        float s2 = (k & 4) ? -1.f : 1.f;
        float X = qx + s0 * h0x + s1 * h1x + s2 * h2x;
        float Y = qy + s0 * h0y + s1 * h1y + s2 * h2y;
        float Z = qz + s0 * h0z + s1 * h1z + s2 * h2z;
        float gxc = 2.f * (X / Z) / imw1 - 1.f;
        float gyc = 2.f * (Y / Z) / imh1 - 1.f;
        m = m || (fabsf(gxc) <= 1.1f && fabsf(gyc) <= 1.1f && Z > 0.f);
      }
      float mkv = m ? 1.f : 0.f;
      mk[v] = mkv;
      zsum += pz * mkv;
      msum += mkv;

      float x = fminf(fmaxf(px / pz, 0.f), (float)(WFF - 1));
      float y = fminf(fmaxf(py / pz, 0.f), (float)(HFF - 1));
      float x0f = floorf(x), y0f = floorf(y);
      float fxv = x - x0f, fyv = y - y0f;
      int x0 = (int)x0f, y0 = (int)y0f;
      x0 = min(max(x0, 0), WFF - 1);
      y0 = min(max(y0, 0), HFF - 1);
      int x1 = min(x0 + 1, WFF - 1), y1 = min(y0 + 1, HFF - 1);
      base[v] = v * CC * HW + y0 * WFF + x0;
      dxo[v] = (x1 - x0);
      dyo[v] = (y1 - y0) * WFF;
      fx[v] = fxv;
      wa[v] = (1.f - fyv) * mkv;
      wb[v] = fyv * mkv;
    }
    zmean = zsum / (msum + 1e-10f);

    float gram[NPAIR];
#pragma unroll
    for (int p = 0; p < NPAIR; ++p) gram[p] = 0.f;
#pragma unroll 2
    for (int c = 0; c < CC; ++c) {
      float fv[VV];
#pragma unroll
      for (int v = 0; v < VV; ++v) {
        const float* bp = feats + base[v] + c * HW;
        float w00 = (1.f - fx[v]) * wa[v], w01 = fx[v] * wa[v];
        float w10 = (1.f - fx[v]) * wb[v], w11 = fx[v] * wb[v];
        fv[v] = w00 * bp[0] + w01 * bp[dxo[v]] + w10 * bp[dyo[v]] + w11 * bp[dxo[v] + dyo[v]];
      }
      int p = 0;
#pragma unroll
      for (int v = 0; v < VV; ++v)
#pragma unroll
        for (int w = v; w < VV; ++w, ++p) gram[p] += fv[v] * fv[w];
    }

    float inv[VV];
#pragma unroll
    for (int v = 0; v < VV; ++v) inv[v] = 1.f / (sqrtf(gram[triidx(v, v)]) + 1e-10f);

    float logit[VV];
#pragma unroll
    for (int j = 0; j < VV; ++j) logit[j] = sB[j];
    int k = 0;
#pragma unroll
    for (int v = 0; v < VV; ++v) {
#pragma unroll
      for (int w = 0; w < VV; ++w) {
        if (w == v) continue;
        int a = v < w ? v : w, b2 = v < w ? w : v;
        float s = gram[triidx(a, b2)] * inv[v] * inv[w];
#pragma unroll
        for (int j = 0; j < VV; ++j) logit[j] += s * sW[k * VV + j];
        ++k;
      }
    }

    float mx = logit[0];
#pragma unroll
    for (int j = 1; j < VV; ++j) mx = fmaxf(mx, logit[j]);
    float wt[VV], se = 0.f;
#pragma unroll
    for (int j = 0; j < VV; ++j) {
      wt[j] = __expf(logit[j] - mx);
      se += wt[j];
    }
    float rse = 1.f / se;
#pragma unroll
    for (int j = 0; j < VV; ++j) wt[j] = wt[j] * rse * mk[j];

    float* fvrow = out + (size_t)i * (CC + 1);
#pragma unroll 2
    for (int c = 0; c < CC; ++c) {
      float acc = 0.f;
#pragma unroll
      for (int v = 0; v < VV; ++v) {
        const float* bp = feats + base[v] + c * HW;
        float w00 = (1.f - fx[v]) * wa[v], w01 = fx[v] * wa[v];
        float w10 = (1.f - fx[v]) * wb[v], w11 = fx[v] * wb[v];
        float s = w00 * bp[0] + w01 * bp[dxo[v]] + w10 * bp[dyo[v]] + w11 * bp[dxo[v] + dyo[v]];
        acc += wt[v] * s;
      }
      fvrow[c] = acc;
    }
    fvrow[CC] = zmean;

    float* vwrow = out + (size_t)n * (CC + 1) + (size_t)i * VV;
#pragma unroll
    for (int j = 0; j < VV; ++j) vwrow[j] = wt[j];
    out[(size_t)n * (CC + 1) + (size_t)n * VV + i] = msum;
  }

  float zm = active ? zmean : 0.f;
  bool pos = zm > 0.f;
  double s = pos ? (double)zm : 0.0;
  double ss = pos ? (double)zm * (double)zm : 0.0;
  double cn = pos ? 1.0 : 0.0;
#pragma unroll
  for (int off = 32; off > 0; off >>= 1) {
    s += __shfl_down(s, off);
    ss += __shfl_down(ss, off);
    cn += __shfl_down(cn, off);
  }
  int wid = threadIdx.x >> 6, lane = threadIdx.x & 63;
  if (lane == 0) {
    sRed[0][wid] = s;
    sRed[1][wid] = ss;
    sRed[2][wid] = cn;
  }
  __syncthreads();
  if (threadIdx.x == 0) {
    double S = 0, SS = 0, CN = 0;
    for (int w2 = 0; w2 < 4; ++w2) {
      S += sRed[0][w2];
      SS += sRed[1][w2];
      CN += sRed[2][w2];
    }
    partials[blockIdx.x * 3 + 0] = S;
    partials[blockIdx.x * 3 + 1] = SS;
    partials[blockIdx.x * 3 + 2] = CN;
  }
}

__global__ __launch_bounds__(256)
void vf_reduce(const double* __restrict__ partials, int nb, float* __restrict__ musd) {
  __shared__ double sh[3][4];
  double s = 0, ss = 0, cn = 0;
  for (int b = threadIdx.x; b < nb; b += 256) {
    s += partials[b * 3 + 0];
    ss += partials[b * 3 + 1];
    cn += partials[b * 3 + 2];
  }
#pragma unroll
  for (int off = 32; off > 0; off >>= 1) {
    s += __shfl_down(s, off);
    ss += __shfl_down(ss, off);
    cn += __shfl_down(cn, off);
  }
  int wid = threadIdx.x >> 6, lane = threadIdx.x & 63;
  if (lane == 0) {
    sh[0][wid] = s;
    sh[1][wid] = ss;
    sh[2][wid] = cn;
  }
  __syncthreads();
  if (threadIdx.x == 0) {
    double S = 0, SS = 0, CN = 0;
    for (int w2 = 0; w2 < 4; ++w2) {
      S += sh[0][w2];
      SS += sh[1][w2];
      CN += sh[2][w2];
    }
    double cnt = CN < 1.0 ? 1.0 : CN;
    double mu = S / cnt;
    double ssd = SS - 2.0 * mu * S + mu * mu * CN;
    if (ssd < 0.0) ssd = 0.0;
    double sd = sqrt(ssd) + 1e-5;
    musd[0] = (float)mu;
    musd[1] = (float)sd;
  }
}

__global__ __launch_bounds__(256)
void vf_znorm(float* __restrict__ out, const float* __restrict__ musd, int n) {
  int i = blockIdx.x * 256 + threadIdx.x;
  if (i >= n) return;
  float z = out[(size_t)i * (CC + 1) + CC];
  float mu = musd[0], sd = musd[1];
  out[(size_t)i * (CC + 1) + CC] = (z > 0.f) ? (z - mu) / sd : 0.f;
}

extern "C" void kernel_launch(void* const* d_in, const int* in_sizes, int n_in,
                              void* d_out, int out_size, void* d_ws, size_t ws_size,
                              hipStream_t stream) {
  const int* coords = (const int*)d_in[0];
  const float* feats = (const float*)d_in[1];
  const float* proj_feat = (const float*)d_in[2];
  const float* proj_img = (const float*)d_in[3];
  const float* origin = (const float*)d_in[4];
  const float* W_vs = (const float*)d_in[5];
  const float* b_vs = (const float*)d_in[6];
  const float* voxel_size = (const float*)d_in[7];
  const int* scale = (const int*)d_in[8];
  const int* im_h = (const int*)d_in[9];
  const int* im_w = (const int*)d_in[10];

  int n = in_sizes[0] / 4;

  // quad kernel geometry: 64 voxels per block
  int nbq = (n + 63) / 64;
  // fallback geometry: 256 voxels per block
  int nbf = (n + 255) / 256;
  int nb_max = nbq > nbf ? nbq : nbf;

  float* musd = (float*)d_ws;
  double* partials = (double*)((char*)d_ws + 256);
  size_t tf_off = (256 + (size_t)nb_max * 3 * 8 + 255) & ~(size_t)255;
  size_t tf_bytes = (size_t)VV * HW * CC * 4;
  bool use_tr = (ws_size >= tf_off + tf_bytes);
  float* tfeats = (float*)((char*)d_ws + tf_off);

  if (use_tr) {
    int total = VV * HW;
    vf_transpose<<<dim3((total + 255) / 256), dim3(256), 0, stream>>>(feats, tfeats, total);
    vf_main4<<<dim3(nbq), dim3(256), 0, stream>>>(
        coords, tfeats, proj_feat, proj_img, origin, W_vs, b_vs, voxel_size,
        scale, im_h, im_w, (float*)d_out, partials, n);
    vf_reduce<<<dim3(1), dim3(256), 0, stream>>>(partials, nbq, musd);
  } else {
    vf_main_fb<<<dim3(nbf), dim3(256), 0, stream>>>(
        coords, feats, proj_feat, proj_img, origin, W_vs, b_vs, voxel_size,
        scale, im_h, im_w, (float*)d_out, partials, n);
    vf_reduce<<<dim3(1), dim3(256), 0, stream>>>(partials, nbf, musd);
  }
  vf_znorm<<<dim3((n + 255) / 256), dim3(256), 0, stream>>>((float*)d_out, musd, n);
}